// Round 14
// baseline (143.569 us; speedup 1.0000x reference)
//
#include <hip/hip_runtime.h>
#include <hip/hip_fp16.h>
#include <math.h>

// Attention_57406532878693: T=2048,B=32,D=1024,H=8,N=128,N2=16
#define T_   2048
#define B_   32
#define D_   1024
#define H_   8
#define N_   128
#define NK   16          // N2 gate width
#define TSPL 8           // T-splits per (b,h)
#define TBLK (T_/TSPL)   // 256 t per unit
#define BD4  (B_*D_/4)
#define APS  132         // attp stride per unit (128 c + Z + pad)
#define LOG2E 1.4426950408889634f

typedef __attribute__((ext_vector_type(8))) _Float16 half8;  // fp16x8 frag
typedef __attribute__((ext_vector_type(4))) float f32x4;     // native 4xf32

// convert 8 fp32 (two f32x4) to fp16 fragment (RNE)
__device__ __forceinline__ half8 to_half8(f32x4 a, f32x4 b) {
    half8 r;
    r[0] = (_Float16)a.x; r[1] = (_Float16)a.y;
    r[2] = (_Float16)a.z; r[3] = (_Float16)a.w;
    r[4] = (_Float16)b.x; r[5] = (_Float16)b.y;
    r[6] = (_Float16)b.z; r[7] = (_Float16)b.w;
    return r;
}

__device__ __forceinline__ float tanh_fast(float d) {
    return 1.f - 2.f * __frcp_rn(exp2f(d * (2.f * LOG2E)) + 1.f);
}

// nontemporal load of 8 f32x4 of x for one 16-t step (x is read ONCE ever:
// don't fill L2/L3 with it — reserve cache for xc + P)
#define LOADX_NT(dst, step_) { \
    const int trow_ = t0 + (step_) * 64 + w * 16 + kk; \
    const size_t rb_ = (size_t)trow_ * BD4 + base4; \
    (dst)[0] = __builtin_nontemporal_load(&hyp4n[rb_ + g * 2]); \
    (dst)[1] = __builtin_nontemporal_load(&hyp4n[rb_ + g * 2 + 1]); \
    (dst)[2] = __builtin_nontemporal_load(&hyp4n[rb_ + 8 + g * 2]); \
    (dst)[3] = __builtin_nontemporal_load(&hyp4n[rb_ + 8 + g * 2 + 1]); \
    (dst)[4] = __builtin_nontemporal_load(&hyp4n[rb_ + 16 + g * 2]); \
    (dst)[5] = __builtin_nontemporal_load(&hyp4n[rb_ + 16 + g * 2 + 1]); \
    (dst)[6] = __builtin_nontemporal_load(&hyp4n[rb_ + 24 + g * 2]); \
    (dst)[7] = __builtin_nontemporal_load(&hyp4n[rb_ + 24 + g * 2 + 1]); }

// K1: one block per (bh,spl). One NT x read: colsums -> part[blk][128],
// P[t][k]=tanh(x.Ww+b) -> Pbuf (fp16, cached), xc = fp16(x) (cached; the
// to_half8 conversions are shared with the MFMA operands).
__global__ __launch_bounds__(256, 4) void k_p(const float* __restrict__ hyp,
                                              const float* __restrict__ Ww,
                                              const float* __restrict__ Wb,
                                              float* __restrict__ part,
                                              __half* __restrict__ Pbuf,
                                              __half* __restrict__ xcb) {
    __shared__ float red[4 * N_];
    __shared__ __half Pl[TBLK * NK];     // 8 KB unit P staging
    const int tid  = threadIdx.x;
    const int lane = tid & 63;
    const int w    = tid >> 6;
    const int blk  = blockIdx.x;
    const int bh   = blk >> 3;
    const int spl  = blk & 7;
    const int b = bh >> 3, h = bh & 7;
    const int t0 = spl * TBLK;
    const f32x4* hyp4n = (const f32x4*)hyp;
    const f32x4* Ww4   = (const f32x4*)Ww;
    const int base4 = b * (D_ / 4) + h * (N_ / 4);
    const int kk = lane & 15;
    const int g  = lane >> 4;

    half8 wf[4];
#pragma unroll
    for (int ks = 0; ks < 4; ++ks) {
        f32x4 wa  = Ww4[kk * 32 + ks * 8 + g * 2];
        f32x4 wb4 = Ww4[kk * 32 + ks * 8 + g * 2 + 1];
        wf[ks] = to_half8(wa, wb4);
    }
    const float wbr = Wb[kk];

    f32x4 cs[8];
#pragma unroll
    for (int m = 0; m < 8; ++m) cs[m] = (f32x4){0.f, 0.f, 0.f, 0.f};

#pragma unroll
    for (int step = 0; step < 4; ++step) {
        f32x4 xq[8];
        LOADX_NT(xq, step);
        const int trow = t0 + step * 64 + w * 16 + kk;
        __half* xrow = xcb + ((size_t)bh * T_ + trow) * N_;
#pragma unroll
        for (int m = 0; m < 8; ++m) {
            cs[m].x += xq[m].x; cs[m].y += xq[m].y;
            cs[m].z += xq[m].z; cs[m].w += xq[m].w;
        }
        f32x4 acc = {0.f, 0.f, 0.f, 0.f};
#pragma unroll
        for (int ks = 0; ks < 4; ++ks) {
            half8 xf = to_half8(xq[2*ks], xq[2*ks+1]);
            acc = __builtin_amdgcn_mfma_f32_16x16x32_f16(xf, wf[ks], acc, 0, 0, 0);
            *(half8*)&xrow[ks * 32 + g * 8] = xf;   // 16B store, 64B/row segs
        }
        // stage P[t_local = step*64+w*16+g*4+i][kk] in LDS
        const int tl = step * 64 + w * 16 + g * 4;
#pragma unroll
        for (int i = 0; i < 4; ++i)
            Pl[(tl + i) * NK + kk] = __float2half(tanh_fast(acc[i] + wbr));
    }
    __syncthreads();
    // coalesced flush: 8 KB contiguous (unit is t-major inside bh)
    {
        const uint4* src = (const uint4*)Pl;
        uint4* dst = (uint4*)(Pbuf + ((size_t)bh * T_ + t0) * NK);
        dst[tid]       = src[tid];
        dst[tid + 256] = src[tid + 256];
    }
    // reduce colsums over kk (lane bits 0-3)
#pragma unroll
    for (int m = 0; m < 8; ++m) {
#pragma unroll
        for (int mask = 1; mask <= 8; mask <<= 1) {
            cs[m].x += __shfl_xor(cs[m].x, mask, 64);
            cs[m].y += __shfl_xor(cs[m].y, mask, 64);
            cs[m].z += __shfl_xor(cs[m].z, mask, 64);
            cs[m].w += __shfl_xor(cs[m].w, mask, 64);
        }
    }
    if (kk == 0) {
#pragma unroll
        for (int m = 0; m < 8; ++m) {
            int nb = 32 * (m >> 1) + 8 * g + 4 * (m & 1);
            red[w * N_ + nb + 0] = cs[m].x;
            red[w * N_ + nb + 1] = cs[m].y;
            red[w * N_ + nb + 2] = cs[m].z;
            red[w * N_ + nb + 3] = cs[m].w;
        }
    }
    __syncthreads();
    if (tid < N_)
        part[blk * N_ + tid] = (red[tid] + red[N_ + tid])
                             + (red[2*N_ + tid] + red[3*N_ + tid]);
}

// K2: one block per (bh,spl), identity order (same-XCD as producer).
// Phase 1: thread=t computes e_t from its 32B P row (L3-hot). Phase 2:
// thread=(c8,tg) accumulates e_t * xc[t][c8*8..+7] — fp16 rows, 256B/row,
// perfectly coalesced, mostly L3-served.
__global__ __launch_bounds__(256, 4) void k_att(const __half* __restrict__ xcb,
                                                const float* __restrict__ part,
                                                const float* __restrict__ Wmw,
                                                const float* __restrict__ Wmb,
                                                const float* __restrict__ Whw,
                                                const __half* __restrict__ Pbuf,
                                                float* __restrict__ attp) {
    __shared__ float m_l[N_];
    __shared__ float gw_l[NK];
    __shared__ float wexp_l[TBLK];       // 1 KB: e_t for the unit
    __shared__ float4 redc[16][16][2];   // 8 KB: [tg][c8][half] partials
    __shared__ float zred[4];
    const int tid  = threadIdx.x;
    const int lane = tid & 63;
    const int w    = tid >> 6;
    const int blk  = (int)blockIdx.x;
    const int bh   = blk >> 3;
    const int spl  = blk & 7;
    const int t0 = spl * TBLK;

    // mean for this bh
    if (tid < N_) {
        float s = 0.f;
#pragma unroll
        for (int s8 = 0; s8 < TSPL; ++s8) s += part[(bh * TSPL + s8) * N_ + tid];
        m_l[tid] = s * (1.f / (float)T_);
    }
    __syncthreads();
    // gm: gw_l[k] = tanh(m.Wmw_k + Wmb_k) * Whw_k
    if (tid < N_) {
        int k = tid >> 3, g3 = tid & 7;
        float dsum = 0.f;
#pragma unroll
        for (int i = 0; i < 16; ++i) {
            int n = g3 * 16 + i;
            dsum = fmaf(m_l[n], Wmw[k * N_ + n], dsum);
        }
        dsum += __shfl_xor(dsum, 1, 64);
        dsum += __shfl_xor(dsum, 2, 64);
        dsum += __shfl_xor(dsum, 4, 64);
        if (g3 == 0) gw_l[k] = tanhf(dsum + Wmb[k]) * Whw[k];
    }
    __syncthreads();

    // ---- phase 1: thread t = t0 + tid computes e_t (coalesced P read) ----
    {
        const uint4* pv = (const uint4*)(Pbuf + ((size_t)bh * T_ + t0) * NK);
        union { uint4 u; __half2 hh[4]; } Pa, Pb;
        Pa.u = pv[2 * tid];
        Pb.u = pv[2 * tid + 1];
        float lg = 0.f;
#pragma unroll
        for (int q = 0; q < 4; ++q) {
            float2 f0 = __half22float2(Pa.hh[q]);
            float2 f1 = __half22float2(Pb.hh[q]);
            lg = fmaf(f0.x, gw_l[2*q + 0], lg);
            lg = fmaf(f0.y, gw_l[2*q + 1], lg);
            lg = fmaf(f1.x, gw_l[8 + 2*q + 0], lg);
            lg = fmaf(f1.y, gw_l[8 + 2*q + 1], lg);
        }
        float e = exp2f(lg * LOG2E);     // unshifted: |lg| <= sum|Whw| <= 4
        wexp_l[tid] = e;
        float z = e;
        z += __shfl_xor(z, 1, 64);  z += __shfl_xor(z, 2, 64);
        z += __shfl_xor(z, 4, 64);  z += __shfl_xor(z, 8, 64);
        z += __shfl_xor(z, 16, 64); z += __shfl_xor(z, 32, 64);
        if (lane == 0) zred[w] = z;
    }
    __syncthreads();

    // ---- phase 2: thread (c8, tg): 16 t's of fp16 x chunk, coalesced ----
    const int c8 = tid & 15, tg = tid >> 4;
    float4 c0 = {0.f,0.f,0.f,0.f}, c1 = {0.f,0.f,0.f,0.f};
    const float* we = &wexp_l[tg * 16];
    const __half* xr = xcb + ((size_t)bh * T_ + t0 + tg * 16) * N_ + c8 * 8;
#pragma unroll
    for (int i = 0; i < 16; ++i) {
        union { uint4 u; __half2 hh[4]; } X;
        X.u = *(const uint4*)(xr + (size_t)i * N_);
        float e = we[i];
        float2 f0 = __half22float2(X.hh[0]);
        float2 f1 = __half22float2(X.hh[1]);
        float2 f2 = __half22float2(X.hh[2]);
        float2 f3 = __half22float2(X.hh[3]);
        c0.x = fmaf(e, f0.x, c0.x); c0.y = fmaf(e, f0.y, c0.y);
        c0.z = fmaf(e, f1.x, c0.z); c0.w = fmaf(e, f1.y, c0.w);
        c1.x = fmaf(e, f2.x, c1.x); c1.y = fmaf(e, f2.y, c1.y);
        c1.z = fmaf(e, f3.x, c1.z); c1.w = fmaf(e, f3.y, c1.w);
    }
    redc[tg][c8][0] = c0;
    redc[tg][c8][1] = c1;
    __syncthreads();
    if (tid < N_) {
        int cc8 = tid >> 3, jj = tid & 7;
        float s = 0.f;
#pragma unroll
        for (int g16 = 0; g16 < 16; ++g16) {
            const float* rr = (const float*)&redc[g16][cc8][0];
            s += rr[jj];
        }
        attp[(size_t)blk * APS + tid] = s;
    } else if (tid == N_) {
        attp[(size_t)blk * APS + N_] =
            (zred[0] + zred[1]) + (zred[2] + zred[3]);
    }
}

// K4: merge TSPL split partials per (b,h): c = sum ci / sum Zi
__global__ __launch_bounds__(128) void k_red(const float* __restrict__ attp,
                                             float* __restrict__ out) {
    int bh = blockIdx.x, tid = threadIdx.x;
    float Z = 0.f, c = 0.f;
#pragma unroll
    for (int s = 0; s < TSPL; ++s) {
        const float* pp = &attp[(size_t)(bh * TSPL + s) * APS];
        Z += pp[N_];
        c += pp[tid];
    }
    out[bh * N_ + tid] = c / Z;
}

extern "C" void kernel_launch(void* const* d_in, const int* in_sizes, int n_in,
                              void* d_out, int out_size, void* d_ws, size_t ws_size,
                              hipStream_t stream) {
    const float* hyp = (const float*)d_in[0];
    const float* Ww  = (const float*)d_in[1];
    const float* Wb  = (const float*)d_in[2];
    const float* Wmw = (const float*)d_in[3];
    const float* Wmb = (const float*)d_in[4];
    const float* Whw = (const float*)d_in[5];
    // d_in[6] = Wh_b: unused (softmax shift-invariant)
    float* out  = (float*)d_out;
    float* part = (float*)d_ws;                  // 2048*128 f  = 1 MB
    float* attp = part + 2048 * N_;              // 2048*132 f ~= 1.06 MB
    __half* Pbuf = (__half*)((char*)d_ws + (4 << 20));   // 16 MB fp16 P
    __half* xcb  = (__half*)((char*)d_ws + (24 << 20));  // 128 MB fp16 x

    k_p  <<<dim3(B_ * H_ * TSPL), 256, 0, stream>>>(hyp, Ww, Wb, part, Pbuf,
                                                    xcb);
    k_att<<<dim3(B_ * H_ * TSPL), 256, 0, stream>>>(xcb, part, Wmw, Wmb, Whw,
                                                    Pbuf, attp);
    k_red<<<dim3(B_ * H_), 128, 0, stream>>>(attp, out);
}